// Round 11
// baseline (286.408 us; speedup 1.0000x reference)
//
#include <hip/hip_runtime.h>
#include <math.h>

#define B_  4
#define S_  2048
#define D_  1024
#define H_  16
#define HD_ 64
#define M_  (B_*S_)

typedef unsigned int  uint;
typedef unsigned short ushort;

typedef __attribute__((ext_vector_type(8))) short bf16x8;   // 8 bf16 = 4 VGPRs
typedef __attribute__((ext_vector_type(4))) float f32x4;

#if __has_builtin(__builtin_amdgcn_exp2f)
#define EXP2(x) __builtin_amdgcn_exp2f(x)
#else
#define EXP2(x) exp2f(x)
#endif

#define GPTR(p) (const __attribute__((address_space(1))) void*)(p)
#define LPTR(p) (__attribute__((address_space(3))) void*)(p)

// ---------------------------------------------------------------- helpers
__device__ __forceinline__ ushort f2bf(float x) {
    uint u = __float_as_uint(x);
    u += 0x7FFFu + ((u >> 16) & 1u);      // RNE
    return (ushort)(u >> 16);
}
__device__ __forceinline__ uint pack2bf(float a, float b) {
    uint ua = __float_as_uint(a); ua += 0x7FFFu + ((ua >> 16) & 1u);
    uint ub = __float_as_uint(b); ub += 0x7FFFu + ((ub >> 16) & 1u);
    return (ua >> 16) | (ub & 0xFFFF0000u);
}

// ---------------- prep: x->bf16  +  4x W[K,N] -> Wt[N,K] bf16 --------------
// grid (4096, 1, 2).  z=0: cvt x (4096 blocks exact).  z=1: 4x1024 wtrans.
__global__ __launch_bounds__(256) void prep(const float* __restrict__ x,
                                            ushort* __restrict__ xb,
                                            const float* __restrict__ Wq,
                                            const float* __restrict__ Wk,
                                            const float* __restrict__ Wv,
                                            const float* __restrict__ Wp,
                                            ushort* __restrict__ wtq,
                                            ushort* __restrict__ wtk,
                                            ushort* __restrict__ wtv,
                                            ushort* __restrict__ wtp) {
    __shared__ float t[32][33];
    const int tid = threadIdx.x;
    if (blockIdx.z == 0) {
        const int idx = blockIdx.x * 256 + tid;           // < M_*D_/8 exactly
        const float4* p = (const float4*)(x + (size_t)idx * 8);
        float4 a = p[0], b = p[1];
        uint4 o;
        o.x = pack2bf(a.x, a.y); o.y = pack2bf(a.z, a.w);
        o.z = pack2bf(b.x, b.y); o.w = pack2bf(b.z, b.w);
        ((uint4*)xb)[idx] = o;
    } else {
        const int w = blockIdx.x >> 10;                   // which weight
        const int sub = blockIdx.x & 1023;
        const float* W = (w == 0) ? Wq : (w == 1) ? Wk : (w == 2) ? Wv : Wp;
        ushort* Wt     = (w == 0) ? wtq : (w == 1) ? wtk : (w == 2) ? wtv : wtp;
        const int nb = (sub & 31) * 32, kb = (sub >> 5) * 32;
        #pragma unroll
        for (int l = 0; l < 4; ++l) {
            int idx = tid + l * 256;
            int r = idx >> 5, c = idx & 31;
            t[r][c] = W[(size_t)(kb + r) * D_ + nb + c];
        }
        __syncthreads();
        #pragma unroll
        for (int l = 0; l < 4; ++l) {
            int idx = tid + l * 256;
            int nr = idx >> 5, kc = idx & 31;
            Wt[(size_t)(nb + nr) * D_ + kb + kc] = f2bf(t[kc][nr]);
        }
    }
}

// ================= qkvt: 128x256-tile, 8-wave, 3-buffer counted-vmcnt ======
// R10 post-mortem: counted-vmcnt at 128²/4-wave = null (m232 regime gate);
// qkvt was at the 2-phase structural ceiling (~717 TF). R11 structure:
// BM=128, BN=256, BK=32, 512 thr = 8 waves (2M x 4N), per-wave 64x64 out
// (same per-thread frag pattern as the proven R8 kernel, ~80-100 VGPR).
// Grid (64,4,3) = 768 blocks = exactly 3 full CU-rounds. LDS = 3-buffer ring
// (72 KB -> 2 blocks/CU), compile-time buffer indices via x3-unrolled steps.
// Per tile T: { vmcnt(3) [T's 3 stage-loads drained, T+1's stay in flight];
// s_barrier; STAGE(T+2 -> ring buf, never a live buffer); ds_read x8;
// setprio(1); 16 MFMA; setprio(0) }. One barrier per tile. Stage has ~2
// tiles of compute to land. Swizzle: 64-B rows, X(row)=((row>>1)&3)<<4 both
// sides (0 conflicts, proven R8).
struct QLds {
    ushort As[3][128 * 32];   // 3 x 8 KB  (tokens x K)
    ushort Bs[3][256 * 32];   // 3 x 16 KB (features x K)
};

#define QSTAGE(tile_, buf_) do {                                                \
    const int ko_ = (tile_) * 64;                                               \
    __builtin_amdgcn_global_load_lds(GPTR(Ab + ko_ + sgA),                      \
        LPTR(&L.As[buf_][wave * 512]), 16, 0, 0);                               \
    __builtin_amdgcn_global_load_lds(GPTR(Bb + ko_ + sgB0),                     \
        LPTR(&L.Bs[buf_][wave * 512]), 16, 0, 0);                               \
    __builtin_amdgcn_global_load_lds(GPTR(Bb + ko_ + sgB1),                     \
        LPTR(&L.Bs[buf_][4096 + wave * 512]), 16, 0, 0);                        \
} while (0)

#define QCOMPUTE(buf_) do {                                                     \
    const char* As_ = (const char*)L.As[buf_];                                  \
    const char* Bs_ = (const char*)L.Bs[buf_];                                  \
    bf16x8 af[4], bf[4];                                                        \
    _Pragma("unroll")                                                           \
    for (int i_ = 0; i_ < 4; ++i_)                                              \
        af[i_] = *(const bf16x8*)(As_ + (wm + 16 * i_ + fr) * 64 + ((fq * 16) ^ xrw)); \
    _Pragma("unroll")                                                           \
    for (int j_ = 0; j_ < 4; ++j_)                                              \
        bf[j_] = *(const bf16x8*)(Bs_ + (wn + 16 * j_ + fr) * 64 + ((fq * 16) ^ xrw)); \
    __builtin_amdgcn_s_setprio(1);                                              \
    _Pragma("unroll")                                                           \
    for (int i_ = 0; i_ < 4; ++i_)                                              \
        _Pragma("unroll")                                                       \
        for (int j_ = 0; j_ < 4; ++j_)                                          \
            acc[i_][j_] = SWAP                                                  \
                ? __builtin_amdgcn_mfma_f32_16x16x32_bf16(bf[j_], af[i_], acc[i_][j_], 0, 0, 0) \
                : __builtin_amdgcn_mfma_f32_16x16x32_bf16(af[i_], bf[j_], acc[i_][j_], 0, 0, 0); \
    __builtin_amdgcn_s_setprio(0);                                              \
} while (0)

#define QSTEP(buf_, sbuf_, stile_) do {                                         \
    asm volatile("s_waitcnt vmcnt(3)" ::: "memory");                            \
    __builtin_amdgcn_s_barrier();                                               \
    QSTAGE(stile_, sbuf_);                                                      \
    QCOMPUTE(buf_);                                                             \
} while (0)

template <bool SWAP>
__device__ __forceinline__ void qcore(QLds& L,
                                      const ushort* __restrict__ A,
                                      const ushort* __restrict__ Bt,
                                      f32x4 acc[4][4], int m0, int n0) {
    const int tid  = threadIdx.x;
    const int wave = tid >> 6, lane = tid & 63;
    const int wm = (wave >> 2) * 64;           // 2 M-waves
    const int wn = (wave & 3) * 64;            // 4 N-waves
    const int fr = lane & 15, fq = lane >> 4;
    const int xrw = ((fr >> 1) & 3) << 4;      // read-side XOR: row bits 1-2

    // pre-swizzled global source offsets (LDS dest is linear; involution)
    int sgA, sgB0, sgB1;
    {
        int o = tid * 16;                      // A: 128 rows x 64 B
        int r = o >> 6, c = o & 63;
        sgA = r * (D_ * 2) + (c ^ (((r >> 1) & 3) << 4));
        // B: 256 rows x 64 B, two 8 KB insts
        sgB0 = sgA;                            // same r,c mapping for rows 0-127
        o = 8192 + tid * 16;
        r = o >> 6; c = o & 63;
        sgB1 = r * (D_ * 2) + (c ^ (((r >> 1) & 3) << 4));
    }

    #pragma unroll
    for (int i = 0; i < 4; ++i)
        #pragma unroll
        for (int j = 0; j < 4; ++j) acc[i][j] = (f32x4){0.f, 0.f, 0.f, 0.f};

    const char* Ab = (const char*)A + (size_t)m0 * (D_ * 2);
    const char* Bb = (const char*)Bt + (size_t)n0 * (D_ * 2);

    // prologue: tiles 0,1 staged (6 loads)
    QSTAGE(0, 0);
    QSTAGE(1, 1);

    // 32 K-tiles total; t = 0..29 in 10 static-ring iterations
    #pragma unroll 1
    for (int it = 0; it < 10; ++it) {
        const int t0 = it * 3;
        QSTEP(0, 2, t0 + 2);
        QSTEP(1, 0, t0 + 3);
        QSTEP(2, 1, t0 + 4);
    }
    // t = 30 (buf 0): tile 31's 3 loads may stay in flight
    asm volatile("s_waitcnt vmcnt(3)" ::: "memory");
    __builtin_amdgcn_s_barrier();
    QCOMPUTE(0);
    // t = 31 (buf 1): drain all
    asm volatile("s_waitcnt vmcnt(0)" ::: "memory");
    __builtin_amdgcn_s_barrier();
    QCOMPUTE(1);
}

// fused Q / K / V^T projections.  grid (64, 4, 3): x=token tile (128),
// y=feature tile (256).  Q pre-scaled by 0.125*log2(e).  uint2 stores.
__global__ __launch_bounds__(512, 4) void gemm_qkvt(const ushort* __restrict__ xb,
                                                    const ushort* __restrict__ wtq,
                                                    const ushort* __restrict__ wtk,
                                                    const ushort* __restrict__ wtv,
                                                    const float* __restrict__ bq,
                                                    const float* __restrict__ bk,
                                                    const float* __restrict__ bv,
                                                    ushort* __restrict__ qb,
                                                    ushort* __restrict__ kb,
                                                    ushort* __restrict__ vtb) {
    __shared__ __align__(16) QLds L;           // ONE allocation for both paths
    const int z = blockIdx.z;
    const int lane = threadIdx.x & 63, wave = threadIdx.x >> 6;
    const int wm = (wave >> 2) * 64, wn = (wave & 3) * 64;
    const int cc = lane & 15, fq = lane >> 4;
    const int m0 = blockIdx.x * 128, n0 = blockIdx.y * 256;   // token, feature
    f32x4 acc[4][4];

    if (z < 2) {
        qcore<true>(L, xb, z ? wtk : wtq, acc, m0, n0);
        const float* bias = z ? bk : bq;
        ushort* C = z ? kb : qb;
        const float sc = z ? 1.0f : 0.18033688f;   // 0.125 * log2(e) folded into Q
        #pragma unroll
        for (int j = 0; j < 4; ++j) {
            const int f0 = n0 + wn + 16 * j + fq * 4;    // 4 consecutive features
            const float4 bs4 = *(const float4*)&bias[f0];
            const int h = f0 >> 6, hd = f0 & 63;
            #pragma unroll
            for (int i = 0; i < 4; ++i) {
                const int token = m0 + wm + 16 * i + cc;
                const int bb = token >> 11, s = token & 2047;
                const float v0 = (acc[i][j][0] + bs4.x) * sc;
                const float v1 = (acc[i][j][1] + bs4.y) * sc;
                const float v2 = (acc[i][j][2] + bs4.z) * sc;
                const float v3 = (acc[i][j][3] + bs4.w) * sc;
                uint2 w; w.x = pack2bf(v0, v1); w.y = pack2bf(v2, v3);
                *(uint2*)&C[(((size_t)bb * H_ + h) * S_ + s) * HD_ + hd] = w;
            }
        }
    } else {
        qcore<false>(L, xb, wtv, acc, m0, n0);
        #pragma unroll
        for (int i = 0; i < 4; ++i) {
            const int t0 = m0 + wm + 16 * i + fq * 4;    // 4 consecutive tokens
            const int bb = t0 >> 11, s = t0 & 2047;
            #pragma unroll
            for (int j = 0; j < 4; ++j) {
                const int f = n0 + wn + 16 * j + cc;
                const float bs = bv[f];
                const int h = f >> 6, hd = f & 63;
                uint2 w;
                w.x = pack2bf(acc[i][j][0] + bs, acc[i][j][1] + bs);
                w.y = pack2bf(acc[i][j][2] + bs, acc[i][j][3] + bs);
                *(uint2*)&vtb[(((size_t)bb * H_ + h) * HD_ + hd) * S_ + s] = w;
            }
        }
    }
}

// ---------------- gemm_p core: R8-exact 2-buffer 128² (known 71.9-era) -----
#define GM 128
#define GN 128
#define GK 32

struct PLds {
    ushort As[2][GM * GK];   // 2 x 8 KB (swizzled 64-B rows)
    ushort Bs[2][GN * GK];
};

#define PSTAGE(koff_, buf_) do {                                                \
    _Pragma("unroll")                                                           \
    for (int it_ = 0; it_ < 2; ++it_) {                                         \
        __builtin_amdgcn_global_load_lds(GPTR(Ab + (koff_) + sg[it_]),          \
            LPTR(&L.As[buf_][(it_ * 256 + wave * 64) * 8]), 16, 0, 0);          \
        __builtin_amdgcn_global_load_lds(GPTR(Bb + (koff_) + sg[it_]),          \
            LPTR(&L.Bs[buf_][(it_ * 256 + wave * 64) * 8]), 16, 0, 0);          \
    } } while (0)

__device__ __forceinline__ void pgemm_core(PLds& L,
                                           const ushort* __restrict__ A,
                                           const ushort* __restrict__ Bt,
                                           f32x4 acc[4][4], int m0, int n0) {
    const int tid  = threadIdx.x;
    const int wave = tid >> 6, lane = tid & 63;
    const int wm = (wave >> 1) * 64, wn = (wave & 1) * 64;
    const int fr = lane & 15, fq = lane >> 4;
    const int xrw = ((fr >> 1) & 3) << 4;

    int sg[2];
    #pragma unroll
    for (int it = 0; it < 2; ++it) {
        const int o = (it * 256 + tid) * 16;
        const int r = o >> 6, c = o & 63;
        sg[it] = r * (D_ * 2) + (c ^ (((r >> 1) & 3) << 4));
    }

    #pragma unroll
    for (int i = 0; i < 4; ++i)
        #pragma unroll
        for (int j = 0; j < 4; ++j) acc[i][j] = (f32x4){0.f, 0.f, 0.f, 0.f};

    const char* Ab = (const char*)A + (size_t)m0 * (D_ * 2);
    const char* Bb = (const char*)Bt + (size_t)n0 * (D_ * 2);

    PSTAGE(0, 0);
    __syncthreads();

    int cur = 0;
    for (int k0 = 0; k0 < D_; k0 += GK) {
        if (k0 + GK < D_) PSTAGE((k0 + GK) * 2, cur ^ 1);

        bf16x8 af[4], bfr[4];
        #pragma unroll
        for (int i = 0; i < 4; ++i)
            af[i] = *(const bf16x8*)((const char*)L.As[cur] + (wm + 16 * i + fr) * 64 + ((fq * 16) ^ xrw));
        #pragma unroll
        for (int j = 0; j < 4; ++j)
            bfr[j] = *(const bf16x8*)((const char*)L.Bs[cur] + (wn + 16 * j + fr) * 64 + ((fq * 16) ^ xrw));
        #pragma unroll
        for (int i = 0; i < 4; ++i)
            #pragma unroll
            for (int j = 0; j < 4; ++j)
                acc[i][j] = __builtin_amdgcn_mfma_f32_16x16x32_bf16(af[i], bfr[j], acc[i][j], 0, 0, 0);

        __syncthreads();
        cur ^= 1;
    }
}

// out-projection: fp32 out [M,D].  grid (8, 64)
__global__ __launch_bounds__(256) void gemm_p(const ushort* __restrict__ A,
                                              const ushort* __restrict__ Bt,
                                              const float* __restrict__ bias,
                                              float* __restrict__ C) {
    __shared__ __align__(16) PLds L;
    const int m0 = blockIdx.y * GM, n0 = blockIdx.x * GN;
    f32x4 acc[4][4];
    pgemm_core(L, A, Bt, acc, m0, n0);

    const int lane = threadIdx.x & 63, wave = threadIdx.x >> 6;
    const int wm = (wave >> 1) * 64, wn = (wave & 1) * 64;
    const int cr = (lane >> 4) * 4, cc = lane & 15;
    #pragma unroll
    for (int j = 0; j < 4; ++j) {
        const int col = n0 + wn + 16 * j + cc;
        const float bs = bias[col];
        #pragma unroll
        for (int i = 0; i < 4; ++i)
            #pragma unroll
            for (int r = 0; r < 4; ++r)
                C[(size_t)(m0 + wm + 16 * i + cr + r) * D_ + col] = acc[i][j][r] + bs;
    }
}

// ---------------- block-cooperative LDS-staged MFMA flash attention --------
// R8 form: 8 waves/block (512 thr), each wave owns 16 q-rows of the block's
// 128-q chunk. KVBLK=64, 2-buffer, STAGE(t+1) then one __syncthreads per
// tile. LDS dest is the WAVE-UNIFORM base &Ks[buf][wave*512] (HW adds
// lane*16). Diagonal pair of tiles peeled; 128-B rows + (fr&7)<<4 XOR.
#define PST 72   // P row stride (ushorts): 64 keys + 8 pad

#define STAGE(kt_, buf_) do {                                                   \
    const int kn_ = (kt_) * 64;                                                 \
    __builtin_amdgcn_global_load_lds(                                           \
        GPTR((const char*)kbase + (size_t)kn_ * 128 + kg),                      \
        LPTR(&Ks[buf_][wave * 512]), 16, 0, 0);                                 \
    __builtin_amdgcn_global_load_lds(                                           \
        GPTR((const char*)vbase + (size_t)kn_ * 2 + vg),                        \
        LPTR(&Vs[buf_][wave * 512]), 16, 0, 0);                                 \
} while (0)

__global__ __launch_bounds__(512, 4) void attn_mfma(const ushort* __restrict__ qb,
                                                    const ushort* __restrict__ kb,
                                                    const ushort* __restrict__ vtb,
                                                    ushort* __restrict__ ob) {
    __shared__ __align__(16) ushort Ks[2][64 * 64];    // 2 x 8 KB (keys x hd)
    __shared__ __align__(16) ushort Vs[2][64 * 64];    // 2 x 8 KB (hd x keys)
    __shared__ __align__(16) ushort Pp[8][16 * PST];   // 18 KB wave-private P

    const int tid = threadIdx.x, wave = tid >> 6, lane = tid & 63;
    const int fr = lane & 15, fq = lane >> 4;
    const int hb = blockIdx.x;                 // 0..63 -> (b,h), XCD-local KV
    const int p  = blockIdx.y;                 // 0..7 pair id
    const int b = hb >> 4, h = hb & 15;
    const size_t bh = (size_t)b * H_ + h;
    const ushort* qbase = qb + bh * S_ * HD_;
    const ushort* kbase = kb + bh * S_ * HD_;
    const ushort* vbase = vtb + bh * HD_ * S_;
    ushort* PpW = Pp[wave];
    const int xrw = (fr & 7) << 4;             // fragment-read XOR (byte)

    int kg, vg;
    {
        const int o = tid * 16;                // 0..8191 (8 KB tile)
        const int r = o >> 7, cS = o & 127;    // 64 rows x 128 B
        kg = r * 128 + (cS ^ ((r & 7) << 4));
        vg = r * (S_ * 2) + (cS ^ ((r & 7) << 4));
    }

    for (int phase = 0; phase < 2; ++phase) {
        const int chunk = phase ? p : (15 - p);
        const int q0 = chunk * 128;
        const int wq0 = q0 + wave * 16;
        const int qrow = wq0 + fr;
        const int ntile = 2 * (chunk + 1);

        bf16x8 qf[2];
        #pragma unroll
        for (int kk = 0; kk < 2; ++kk)
            qf[kk] = *(const bf16x8*)&qbase[(size_t)qrow * HD_ + kk * 32 + fq * 8];

        f32x4 ot[4];
        #pragma unroll
        for (int mt = 0; mt < 4; ++mt) ot[mt] = (f32x4){0.f, 0.f, 0.f, 0.f};
        float lp = 0.f;

        int cur = 0;
        STAGE(0, 0);
        __syncthreads();

        for (int t = 0; t < ntile; ++t) {
            if (t + 1 < ntile) STAGE(t + 1, cur ^ 1);
            const ushort* Kb = Ks[cur];
            const ushort* Vb = Vs[cur];
            const int k0 = t * 64;

            f32x4 st[4];
            #pragma unroll
            for (int mt = 0; mt < 4; ++mt) st[mt] = (f32x4){0.f, 0.f, 0.f, 0.f};

            if (t < ntile - 2) {
                #pragma unroll
                for (int kk = 0; kk < 2; ++kk) {
                    bf16x8 kf[4];
                    #pragma unroll
                    for (int mt = 0; mt < 4; ++mt)
                        kf[mt] = *(const bf16x8*)((const char*)Kb + (mt * 16 + fr) * 128 + ((kk * 64 + fq * 16) ^ xrw));
                    __builtin_amdgcn_s_setprio(1);
                    #pragma unroll
                    for (int mt = 0; mt < 4; ++mt)
                        st[mt] = __builtin_amdgcn_mfma_f32_16x16x32_bf16(kf[mt], qf[kk], st[mt], 0, 0, 0);
                    __builtin_amdgcn_s_setprio(0);
                }
                #pragma unroll
                for (int mt = 0; mt < 4; ++mt) {
                    float pr[4];
                    #pragma unroll
                    for (int r = 0; r < 4; ++r) pr[r] = EXP2(st[mt][r]);
                    lp += (pr[0] + pr[1]) + (pr[2] + pr[3]);
                    uint2 w;
                    w.x = pack2bf(pr[0], pr[1]);
                    w.y = pack2bf(pr[2], pr[3]);
                    *(uint2*)&PpW[fr * PST + mt * 16 + fq * 4] = w;
                }
                #pragma unroll
                for (int kk = 0; kk < 2; ++kk) {
                    bf16x8 vf[4];
                    #pragma unroll
                    for (int mt = 0; mt < 4; ++mt)
                        vf[mt] = *(const bf16x8*)((const char*)Vb + (mt * 16 + fr) * 128 + ((kk * 64 + fq * 16) ^ xrw));
                    bf16x8 pf = *(const bf16x8*)&PpW[fr * PST + kk * 32 + fq * 8];
                    __builtin_amdgcn_s_setprio(1);
                    #pragma unroll
                    for (int mt = 0; mt < 4; ++mt)
                        ot[mt] = __builtin_amdgcn_mfma_f32_16x16x32_bf16(vf[mt], pf, ot[mt], 0, 0, 0);
                    __builtin_amdgcn_s_setprio(0);
                }
            } else {
                #pragma unroll
                for (int kk = 0; kk < 2; ++kk) {
                    bf16x8 kf[4];
                    #pragma unroll
                    for (int mt = 0; mt < 4; ++mt)
                        kf[mt] = *(const bf16x8*)((const char*)Kb + (mt * 16 + fr) * 128 + ((kk * 64 + fq * 16) ^ xrw));
                    #pragma unroll
                    for (int mt = 0; mt < 4; ++mt)
                        if (k0 + mt * 16 <= wq0 + 15)
                            st[mt] = __builtin_amdgcn_mfma_f32_16x16x32_bf16(kf[mt], qf[kk], st[mt], 0, 0, 0);
                }
                #pragma unroll
                for (int mt = 0; mt < 4; ++mt) {
                    const int kb0 = k0 + mt * 16 + fq * 4;
                    float pr[4];
                    #pragma unroll
                    for (int r = 0; r < 4; ++r) {
                        const float e = EXP2(st[mt][r]);
                        pr[r] = (kb0 + r > qrow) ? 0.f : e;
                    }
                    lp += (pr[0] + pr[1]) + (pr[2] + pr[3]);
                    uint2 w;
                    w.x = pack2bf(pr[0], pr[1]);
                    w.y = pack2bf(pr[2], pr[3]);
                    *(uint2*)&PpW[fr * PST + mt * 16 + fq * 4] = w;
                }
                #pragma unroll
                for (int kk = 0; kk < 2; ++kk) {
                    if (k0 + kk * 32 <= wq0 + 15) {
                        bf16x8 vf[4];
                        #pragma unroll
                        for (int mt = 0; mt < 4; ++mt)
                            vf[mt] = *(const bf16x8*)((const char*)Vb + (mt * 16 + fr) * 128 + ((kk * 64 + fq * 16) ^ xrw));
                        bf16x8 pf = *(const bf16x8*)&PpW[fr * PST + kk * 32 + fq * 8];
                        #pragma unroll
                        for (int mt = 0; mt < 4; ++mt)
                            ot[mt] = __builtin_amdgcn_mfma_f32_16x16x32_bf16(vf[mt], pf, ot[mt], 0, 0, 0);
                    }
                }
            }
            __syncthreads();   // drains stage loads + all waves done with cur
            cur ^= 1;
        }

        // epilogue: reduce l over fq lanes, normalize, store O^T -> ob [B,S,D]
        float l = lp;
        l += __shfl_xor(l, 16);
        l += __shfl_xor(l, 32);
        const float inv = 1.0f / l;
        #pragma unroll
        for (int mt = 0; mt < 4; ++mt) {
            uint2 w;
            w.x = pack2bf(ot[mt][0] * inv, ot[mt][1] * inv);
            w.y = pack2bf(ot[mt][2] * inv, ot[mt][3] * inv);
            *(uint2*)&ob[((size_t)b * S_ + qrow) * D_ + h * HD_ + mt * 16 + fq * 4] = w;
        }
    }
}

// ---------------- residual add + LayerNorm ----------------
__global__ __launch_bounds__(256) void resln(float* __restrict__ out,
                                             const float* __restrict__ x,
                                             const float* __restrict__ g,
                                             const float* __restrict__ bb) {
    __shared__ float red[256];
    const int row = blockIdx.x, tid = threadIdx.x;
    const size_t off = (size_t)row * D_ + tid * 4;

    float4 p  = *(const float4*)&out[off];
    float4 xr = *(const float4*)&x[off];
    float4 y  = make_float4(p.x + xr.x, p.y + xr.y, p.z + xr.z, p.w + xr.w);

    float sum = y.x + y.y + y.z + y.w;
    red[tid] = sum;
    __syncthreads();
    #pragma unroll
    for (int st = 128; st > 0; st >>= 1) {
        if (tid < st) red[tid] += red[tid + st];
        __syncthreads();
    }
    const float mu = red[0] * (1.0f / D_);
    __syncthreads();

    float dx = y.x - mu, dy = y.y - mu, dz = y.z - mu, dw = y.w - mu;
    red[tid] = dx * dx + dy * dy + dz * dz + dw * dw;
    __syncthreads();
    #pragma unroll
    for (int st = 128; st > 0; st >>= 1) {
        if (tid < st) red[tid] += red[tid + st];
        __syncthreads();
    }
    const float var = red[0] * (1.0f / D_);
    const float inv = rsqrtf(var + 1e-5f);

    float4 gg = *(const float4*)&g[tid * 4];
    float4 bv = *(const float4*)&bb[tid * 4];
    float4 r;
    r.x = dx * inv * gg.x + bv.x;
    r.y = dy * inv * gg.y + bv.y;
    r.z = dz * inv * gg.z + bv.z;
    r.w = dw * inv * gg.w + bv.w;
    *(float4*)&out[off] = r;
}

extern "C" void kernel_launch(void* const* d_in, const int* in_sizes, int n_in,
                              void* d_out, int out_size, void* d_ws, size_t ws_size,
                              hipStream_t stream) {
    const float* x    = (const float*)d_in[0];
    const float* Wq   = (const float*)d_in[1];
    const float* bq   = (const float*)d_in[2];
    const float* Wk   = (const float*)d_in[3];
    const float* bk   = (const float*)d_in[4];
    const float* Wv   = (const float*)d_in[5];
    const float* bv   = (const float*)d_in[6];
    const float* Wp   = (const float*)d_in[7];
    const float* bp   = (const float*)d_in[8];
    const float* ln_g = (const float*)d_in[9];
    const float* ln_b = (const float*)d_in[10];

    float* out = (float*)d_out;

    char* ws = (char*)d_ws;
    ushort* qb  = (ushort*)ws;
    ushort* kb  = (ushort*)(ws + (size_t)16 * (1 << 20));
    ushort* vtb = (ushort*)(ws + (size_t)32 * (1 << 20));
    ushort* xb  = (ushort*)(ws + (size_t)48 * (1 << 20));
    ushort* ob  = (ushort*)(ws + (size_t)64 * (1 << 20));
    ushort* wtq = (ushort*)(ws + (size_t)80 * (1 << 20));
    ushort* wtk = (ushort*)(ws + (size_t)82 * (1 << 20));
    ushort* wtv = (ushort*)(ws + (size_t)84 * (1 << 20));
    ushort* wtp = (ushort*)(ws + (size_t)86 * (1 << 20));

    // convert x + transpose/convert all 4 weights in one launch
    prep<<<dim3(4096, 1, 2), 256, 0, stream>>>(x, xb, Wq, Wk, Wv, Wp, wtq, wtk, wtv, wtp);

    // Q,K -> [B,H,S,HD]; Vt -> [B,H,HD,S]  (one fused launch, 768 blocks)
    gemm_qkvt<<<dim3(M_ / 128, D_ / 256, 3), 512, 0, stream>>>(
        xb, wtq, wtk, wtv, bq, bk, bv, qb, kb, vtb);

    // block-cooperative LDS-staged flash attention -> ob bf16 [B,S,D]
    attn_mfma<<<dim3(64, 8), 512, 0, stream>>>(qb, kb, vtb, ob);

    // out-projection + residual/LN
    gemm_p<<<dim3(D_ / GN, M_ / GM), 256, 0, stream>>>(ob, wtp, bp, out);
    resln<<<M_, 256, 0, stream>>>(out, x, ln_g, ln_b);
}

// Round 12
// 267.677 us; speedup vs baseline: 1.0700x; 1.0700x over previous
//
#include <hip/hip_runtime.h>
#include <math.h>

#define B_  4
#define S_  2048
#define D_  1024
#define H_  16
#define HD_ 64
#define M_  (B_*S_)

typedef unsigned int  uint;
typedef unsigned short ushort;

typedef __attribute__((ext_vector_type(8))) short bf16x8;   // 8 bf16 = 4 VGPRs
typedef __attribute__((ext_vector_type(4))) float f32x4;

#if __has_builtin(__builtin_amdgcn_exp2f)
#define EXP2(x) __builtin_amdgcn_exp2f(x)
#else
#define EXP2(x) exp2f(x)
#endif

#define GPTR(p) (const __attribute__((address_space(1))) void*)(p)
#define LPTR(p) (__attribute__((address_space(3))) void*)(p)

// ---------------------------------------------------------------- helpers
__device__ __forceinline__ ushort f2bf(float x) {
    uint u = __float_as_uint(x);
    u += 0x7FFFu + ((u >> 16) & 1u);      // RNE
    return (ushort)(u >> 16);
}
__device__ __forceinline__ uint pack2bf(float a, float b) {
    uint ua = __float_as_uint(a); ua += 0x7FFFu + ((ua >> 16) & 1u);
    uint ub = __float_as_uint(b); ub += 0x7FFFu + ((ub >> 16) & 1u);
    return (ua >> 16) | (ub & 0xFFFF0000u);
}
// single-instruction packed f32->bf16 (lo=a, hi=b); attn hot loop only
__device__ __forceinline__ uint cvtpk2bf(float a, float b) {
    uint r;
    asm("v_cvt_pk_bf16_f32 %0, %1, %2" : "=v"(r) : "v"(a), "v"(b));
    return r;
}

// ---------------- prep: x->bf16  +  4x W[K,N] -> Wt[N,K] bf16 --------------
// grid (4096, 1, 2).  z=0: cvt x (4096 blocks exact).  z=1: 4x1024 wtrans.
__global__ __launch_bounds__(256) void prep(const float* __restrict__ x,
                                            ushort* __restrict__ xb,
                                            const float* __restrict__ Wq,
                                            const float* __restrict__ Wk,
                                            const float* __restrict__ Wv,
                                            const float* __restrict__ Wp,
                                            ushort* __restrict__ wtq,
                                            ushort* __restrict__ wtk,
                                            ushort* __restrict__ wtv,
                                            ushort* __restrict__ wtp) {
    __shared__ float t[32][33];
    const int tid = threadIdx.x;
    if (blockIdx.z == 0) {
        const int idx = blockIdx.x * 256 + tid;           // < M_*D_/8 exactly
        const float4* p = (const float4*)(x + (size_t)idx * 8);
        float4 a = p[0], b = p[1];
        uint4 o;
        o.x = pack2bf(a.x, a.y); o.y = pack2bf(a.z, a.w);
        o.z = pack2bf(b.x, b.y); o.w = pack2bf(b.z, b.w);
        ((uint4*)xb)[idx] = o;
    } else {
        const int w = blockIdx.x >> 10;                   // which weight
        const int sub = blockIdx.x & 1023;
        const float* W = (w == 0) ? Wq : (w == 1) ? Wk : (w == 2) ? Wv : Wp;
        ushort* Wt     = (w == 0) ? wtq : (w == 1) ? wtk : (w == 2) ? wtv : wtp;
        const int nb = (sub & 31) * 32, kb = (sub >> 5) * 32;
        #pragma unroll
        for (int l = 0; l < 4; ++l) {
            int idx = tid + l * 256;
            int r = idx >> 5, c = idx & 31;
            t[r][c] = W[(size_t)(kb + r) * D_ + nb + c];
        }
        __syncthreads();
        #pragma unroll
        for (int l = 0; l < 4; ++l) {
            int idx = tid + l * 256;
            int nr = idx >> 5, kc = idx & 31;
            Wt[(size_t)(nb + nr) * D_ + kb + kc] = f2bf(t[kc][nr]);
        }
    }
}

// ================= qkvt: 128x256-tile, 8-wave, 3-buffer counted-vmcnt ======
// (R11 structure, kept: rocprof showed it left the top-5.)
struct QLds {
    ushort As[3][128 * 32];   // 3 x 8 KB  (tokens x K)
    ushort Bs[3][256 * 32];   // 3 x 16 KB (features x K)
};

#define QSTAGE(tile_, buf_) do {                                                \
    const int ko_ = (tile_) * 64;                                               \
    __builtin_amdgcn_global_load_lds(GPTR(Ab + ko_ + sgA),                      \
        LPTR(&L.As[buf_][wave * 512]), 16, 0, 0);                               \
    __builtin_amdgcn_global_load_lds(GPTR(Bb + ko_ + sgB0),                     \
        LPTR(&L.Bs[buf_][wave * 512]), 16, 0, 0);                               \
    __builtin_amdgcn_global_load_lds(GPTR(Bb + ko_ + sgB1),                     \
        LPTR(&L.Bs[buf_][4096 + wave * 512]), 16, 0, 0);                        \
} while (0)

#define QCOMPUTE(buf_) do {                                                     \
    const char* As_ = (const char*)L.As[buf_];                                  \
    const char* Bs_ = (const char*)L.Bs[buf_];                                  \
    bf16x8 af[4], bf[4];                                                        \
    _Pragma("unroll")                                                           \
    for (int i_ = 0; i_ < 4; ++i_)                                              \
        af[i_] = *(const bf16x8*)(As_ + (wm + 16 * i_ + fr) * 64 + ((fq * 16) ^ xrw)); \
    _Pragma("unroll")                                                           \
    for (int j_ = 0; j_ < 4; ++j_)                                              \
        bf[j_] = *(const bf16x8*)(Bs_ + (wn + 16 * j_ + fr) * 64 + ((fq * 16) ^ xrw)); \
    __builtin_amdgcn_s_setprio(1);                                              \
    _Pragma("unroll")                                                           \
    for (int i_ = 0; i_ < 4; ++i_)                                              \
        _Pragma("unroll")                                                       \
        for (int j_ = 0; j_ < 4; ++j_)                                          \
            acc[i_][j_] = SWAP                                                  \
                ? __builtin_amdgcn_mfma_f32_16x16x32_bf16(bf[j_], af[i_], acc[i_][j_], 0, 0, 0) \
                : __builtin_amdgcn_mfma_f32_16x16x32_bf16(af[i_], bf[j_], acc[i_][j_], 0, 0, 0); \
    __builtin_amdgcn_s_setprio(0);                                              \
} while (0)

#define QSTEP(buf_, sbuf_, stile_) do {                                         \
    asm volatile("s_waitcnt vmcnt(3)" ::: "memory");                            \
    __builtin_amdgcn_s_barrier();                                               \
    QSTAGE(stile_, sbuf_);                                                      \
    QCOMPUTE(buf_);                                                             \
} while (0)

template <bool SWAP>
__device__ __forceinline__ void qcore(QLds& L,
                                      const ushort* __restrict__ A,
                                      const ushort* __restrict__ Bt,
                                      f32x4 acc[4][4], int m0, int n0) {
    const int tid  = threadIdx.x;
    const int wave = tid >> 6, lane = tid & 63;
    const int wm = (wave >> 2) * 64;           // 2 M-waves
    const int wn = (wave & 3) * 64;            // 4 N-waves
    const int fr = lane & 15, fq = lane >> 4;
    const int xrw = ((fr >> 1) & 3) << 4;      // read-side XOR: row bits 1-2

    int sgA, sgB0, sgB1;
    {
        int o = tid * 16;                      // A: 128 rows x 64 B
        int r = o >> 6, c = o & 63;
        sgA = r * (D_ * 2) + (c ^ (((r >> 1) & 3) << 4));
        sgB0 = sgA;                            // B rows 0-127 same mapping
        o = 8192 + tid * 16;
        r = o >> 6; c = o & 63;
        sgB1 = r * (D_ * 2) + (c ^ (((r >> 1) & 3) << 4));
    }

    #pragma unroll
    for (int i = 0; i < 4; ++i)
        #pragma unroll
        for (int j = 0; j < 4; ++j) acc[i][j] = (f32x4){0.f, 0.f, 0.f, 0.f};

    const char* Ab = (const char*)A + (size_t)m0 * (D_ * 2);
    const char* Bb = (const char*)Bt + (size_t)n0 * (D_ * 2);

    QSTAGE(0, 0);
    QSTAGE(1, 1);

    #pragma unroll 1
    for (int it = 0; it < 10; ++it) {
        const int t0 = it * 3;
        QSTEP(0, 2, t0 + 2);
        QSTEP(1, 0, t0 + 3);
        QSTEP(2, 1, t0 + 4);
    }
    asm volatile("s_waitcnt vmcnt(3)" ::: "memory");
    __builtin_amdgcn_s_barrier();
    QCOMPUTE(0);
    asm volatile("s_waitcnt vmcnt(0)" ::: "memory");
    __builtin_amdgcn_s_barrier();
    QCOMPUTE(1);
}

// fused Q / K / V^T projections.  grid (64, 4, 3)
__global__ __launch_bounds__(512, 4) void gemm_qkvt(const ushort* __restrict__ xb,
                                                    const ushort* __restrict__ wtq,
                                                    const ushort* __restrict__ wtk,
                                                    const ushort* __restrict__ wtv,
                                                    const float* __restrict__ bq,
                                                    const float* __restrict__ bk,
                                                    const float* __restrict__ bv,
                                                    ushort* __restrict__ qb,
                                                    ushort* __restrict__ kb,
                                                    ushort* __restrict__ vtb) {
    __shared__ __align__(16) QLds L;
    const int z = blockIdx.z;
    const int lane = threadIdx.x & 63, wave = threadIdx.x >> 6;
    const int wm = (wave >> 2) * 64, wn = (wave & 3) * 64;
    const int cc = lane & 15, fq = lane >> 4;
    const int m0 = blockIdx.x * 128, n0 = blockIdx.y * 256;   // token, feature
    f32x4 acc[4][4];

    if (z < 2) {
        qcore<true>(L, xb, z ? wtk : wtq, acc, m0, n0);
        const float* bias = z ? bk : bq;
        ushort* C = z ? kb : qb;
        const float sc = z ? 1.0f : 0.18033688f;   // 0.125 * log2(e) folded into Q
        #pragma unroll
        for (int j = 0; j < 4; ++j) {
            const int f0 = n0 + wn + 16 * j + fq * 4;    // 4 consecutive features
            const float4 bs4 = *(const float4*)&bias[f0];
            const int h = f0 >> 6, hd = f0 & 63;
            #pragma unroll
            for (int i = 0; i < 4; ++i) {
                const int token = m0 + wm + 16 * i + cc;
                const int bb = token >> 11, s = token & 2047;
                const float v0 = (acc[i][j][0] + bs4.x) * sc;
                const float v1 = (acc[i][j][1] + bs4.y) * sc;
                const float v2 = (acc[i][j][2] + bs4.z) * sc;
                const float v3 = (acc[i][j][3] + bs4.w) * sc;
                uint2 w; w.x = pack2bf(v0, v1); w.y = pack2bf(v2, v3);
                *(uint2*)&C[(((size_t)bb * H_ + h) * S_ + s) * HD_ + hd] = w;
            }
        }
    } else {
        qcore<false>(L, xb, wtv, acc, m0, n0);
        #pragma unroll
        for (int i = 0; i < 4; ++i) {
            const int t0 = m0 + wm + 16 * i + fq * 4;    // 4 consecutive tokens
            const int bb = t0 >> 11, s = t0 & 2047;
            #pragma unroll
            for (int j = 0; j < 4; ++j) {
                const int f = n0 + wn + 16 * j + cc;
                const float bs = bv[f];
                const int h = f >> 6, hd = f & 63;
                uint2 w;
                w.x = pack2bf(acc[i][j][0] + bs, acc[i][j][1] + bs);
                w.y = pack2bf(acc[i][j][2] + bs, acc[i][j][3] + bs);
                *(uint2*)&vtb[(((size_t)bb * H_ + h) * HD_ + hd) * S_ + s] = w;
            }
        }
    }
}

// ---------------- gemm_p core: R8-exact 2-buffer 128² ----------------------
#define GM 128
#define GN 128
#define GK 32

struct PLds {
    ushort As[2][GM * GK];   // 2 x 8 KB (swizzled 64-B rows)
    ushort Bs[2][GN * GK];
};

#define PSTAGE(koff_, buf_) do {                                                \
    _Pragma("unroll")                                                           \
    for (int it_ = 0; it_ < 2; ++it_) {                                         \
        __builtin_amdgcn_global_load_lds(GPTR(Ab + (koff_) + sg[it_]),          \
            LPTR(&L.As[buf_][(it_ * 256 + wave * 64) * 8]), 16, 0, 0);          \
        __builtin_amdgcn_global_load_lds(GPTR(Bb + (koff_) + sg[it_]),          \
            LPTR(&L.Bs[buf_][(it_ * 256 + wave * 64) * 8]), 16, 0, 0);          \
    } } while (0)

__device__ __forceinline__ void pgemm_core(PLds& L,
                                           const ushort* __restrict__ A,
                                           const ushort* __restrict__ Bt,
                                           f32x4 acc[4][4], int m0, int n0) {
    const int tid  = threadIdx.x;
    const int wave = tid >> 6, lane = tid & 63;
    const int wm = (wave >> 1) * 64, wn = (wave & 1) * 64;
    const int fr = lane & 15, fq = lane >> 4;
    const int xrw = ((fr >> 1) & 3) << 4;

    int sg[2];
    #pragma unroll
    for (int it = 0; it < 2; ++it) {
        const int o = (it * 256 + tid) * 16;
        const int r = o >> 6, c = o & 63;
        sg[it] = r * (D_ * 2) + (c ^ (((r >> 1) & 3) << 4));
    }

    #pragma unroll
    for (int i = 0; i < 4; ++i)
        #pragma unroll
        for (int j = 0; j < 4; ++j) acc[i][j] = (f32x4){0.f, 0.f, 0.f, 0.f};

    const char* Ab = (const char*)A + (size_t)m0 * (D_ * 2);
    const char* Bb = (const char*)Bt + (size_t)n0 * (D_ * 2);

    PSTAGE(0, 0);
    __syncthreads();

    int cur = 0;
    for (int k0 = 0; k0 < D_; k0 += GK) {
        if (k0 + GK < D_) PSTAGE((k0 + GK) * 2, cur ^ 1);

        bf16x8 af[4], bfr[4];
        #pragma unroll
        for (int i = 0; i < 4; ++i)
            af[i] = *(const bf16x8*)((const char*)L.As[cur] + (wm + 16 * i + fr) * 64 + ((fq * 16) ^ xrw));
        #pragma unroll
        for (int j = 0; j < 4; ++j)
            bfr[j] = *(const bf16x8*)((const char*)L.Bs[cur] + (wn + 16 * j + fr) * 64 + ((fq * 16) ^ xrw));
        #pragma unroll
        for (int i = 0; i < 4; ++i)
            #pragma unroll
            for (int j = 0; j < 4; ++j)
                acc[i][j] = __builtin_amdgcn_mfma_f32_16x16x32_bf16(af[i], bfr[j], acc[i][j], 0, 0, 0);

        __syncthreads();
        cur ^= 1;
    }
}

// out-projection + fused residual add: out = A@Wp^T + bias + x.  grid (8, 64)
__global__ __launch_bounds__(256) void gemm_p(const ushort* __restrict__ A,
                                              const ushort* __restrict__ Bt,
                                              const float* __restrict__ bias,
                                              const float* __restrict__ xres,
                                              float* __restrict__ C) {
    __shared__ __align__(16) PLds L;
    const int m0 = blockIdx.y * GM, n0 = blockIdx.x * GN;
    f32x4 acc[4][4];
    pgemm_core(L, A, Bt, acc, m0, n0);

    const int lane = threadIdx.x & 63, wave = threadIdx.x >> 6;
    const int wm = (wave >> 1) * 64, wn = (wave & 1) * 64;
    const int cr = (lane >> 4) * 4, cc = lane & 15;
    #pragma unroll
    for (int j = 0; j < 4; ++j) {
        const int col = n0 + wn + 16 * j + cc;
        const float bs = bias[col];
        #pragma unroll
        for (int i = 0; i < 4; ++i)
            #pragma unroll
            for (int r = 0; r < 4; ++r) {
                const size_t idx = (size_t)(m0 + wm + 16 * i + cr + r) * D_ + col;
                C[idx] = acc[i][j][r] + bs + xres[idx];
            }
    }
}

// ---------------- block-cooperative LDS-staged MFMA flash attention --------
// R8 structure; R12 change: all f32->bf16 packing in the hot loop uses
// v_cvt_pk_bf16_f32 (1 instr per pair vs ~7 of RNE bit-twiddle). Kernel is
// VALU-issue-bound (R11: VALUBusy 50%, MfmaUtil 20%) and pack2bf was the
// largest removable VALU term (~48 ops/tile).
#define PST 72   // P row stride (ushorts): 64 keys + 8 pad

#define STAGE(kt_, buf_) do {                                                   \
    const int kn_ = (kt_) * 64;                                                 \
    __builtin_amdgcn_global_load_lds(                                           \
        GPTR((const char*)kbase + (size_t)kn_ * 128 + kg),                      \
        LPTR(&Ks[buf_][wave * 512]), 16, 0, 0);                                 \
    __builtin_amdgcn_global_load_lds(                                           \
        GPTR((const char*)vbase + (size_t)kn_ * 2 + vg),                        \
        LPTR(&Vs[buf_][wave * 512]), 16, 0, 0);                                 \
} while (0)

__global__ __launch_bounds__(512, 4) void attn_mfma(const ushort* __restrict__ qb,
                                                    const ushort* __restrict__ kb,
                                                    const ushort* __restrict__ vtb,
                                                    ushort* __restrict__ ob) {
    __shared__ __align__(16) ushort Ks[2][64 * 64];    // 2 x 8 KB (keys x hd)
    __shared__ __align__(16) ushort Vs[2][64 * 64];    // 2 x 8 KB (hd x keys)
    __shared__ __align__(16) ushort Pp[8][16 * PST];   // 18 KB wave-private P

    const int tid = threadIdx.x, wave = tid >> 6, lane = tid & 63;
    const int fr = lane & 15, fq = lane >> 4;
    const int hb = blockIdx.x;                 // 0..63 -> (b,h), XCD-local KV
    const int p  = blockIdx.y;                 // 0..7 pair id
    const int b = hb >> 4, h = hb & 15;
    const size_t bh = (size_t)b * H_ + h;
    const ushort* qbase = qb + bh * S_ * HD_;
    const ushort* kbase = kb + bh * S_ * HD_;
    const ushort* vbase = vtb + bh * HD_ * S_;
    ushort* PpW = Pp[wave];
    const int xrw = (fr & 7) << 4;             // fragment-read XOR (byte)

    int kg, vg;
    {
        const int o = tid * 16;                // 0..8191 (8 KB tile)
        const int r = o >> 7, cS = o & 127;    // 64 rows x 128 B
        kg = r * 128 + (cS ^ ((r & 7) << 4));
        vg = r * (S_ * 2) + (cS ^ ((r & 7) << 4));
    }

    for (int phase = 0; phase < 2; ++phase) {
        const int chunk = phase ? p : (15 - p);
        const int q0 = chunk * 128;
        const int wq0 = q0 + wave * 16;
        const int qrow = wq0 + fr;
        const int ntile = 2 * (chunk + 1);

        bf16x8 qf[2];
        #pragma unroll
        for (int kk = 0; kk < 2; ++kk)
            qf[kk] = *(const bf16x8*)&qbase[(size_t)qrow * HD_ + kk * 32 + fq * 8];

        f32x4 ot[4];
        #pragma unroll
        for (int mt = 0; mt < 4; ++mt) ot[mt] = (f32x4){0.f, 0.f, 0.f, 0.f};
        float lp = 0.f;

        int cur = 0;
        STAGE(0, 0);
        __syncthreads();

        for (int t = 0; t < ntile; ++t) {
            if (t + 1 < ntile) STAGE(t + 1, cur ^ 1);
            const ushort* Kb = Ks[cur];
            const ushort* Vb = Vs[cur];
            const int k0 = t * 64;

            f32x4 st[4];
            #pragma unroll
            for (int mt = 0; mt < 4; ++mt) st[mt] = (f32x4){0.f, 0.f, 0.f, 0.f};

            if (t < ntile - 2) {
                #pragma unroll
                for (int kk = 0; kk < 2; ++kk) {
                    bf16x8 kf[4];
                    #pragma unroll
                    for (int mt = 0; mt < 4; ++mt)
                        kf[mt] = *(const bf16x8*)((const char*)Kb + (mt * 16 + fr) * 128 + ((kk * 64 + fq * 16) ^ xrw));
                    __builtin_amdgcn_s_setprio(1);
                    #pragma unroll
                    for (int mt = 0; mt < 4; ++mt)
                        st[mt] = __builtin_amdgcn_mfma_f32_16x16x32_bf16(kf[mt], qf[kk], st[mt], 0, 0, 0);
                    __builtin_amdgcn_s_setprio(0);
                }
                #pragma unroll
                for (int mt = 0; mt < 4; ++mt) {
                    float pr[4];
                    #pragma unroll
                    for (int r = 0; r < 4; ++r) pr[r] = EXP2(st[mt][r]);
                    lp += (pr[0] + pr[1]) + (pr[2] + pr[3]);
                    uint2 w;
                    w.x = cvtpk2bf(pr[0], pr[1]);
                    w.y = cvtpk2bf(pr[2], pr[3]);
                    *(uint2*)&PpW[fr * PST + mt * 16 + fq * 4] = w;
                }
                #pragma unroll
                for (int kk = 0; kk < 2; ++kk) {
                    bf16x8 vf[4];
                    #pragma unroll
                    for (int mt = 0; mt < 4; ++mt)
                        vf[mt] = *(const bf16x8*)((const char*)Vb + (mt * 16 + fr) * 128 + ((kk * 64 + fq * 16) ^ xrw));
                    bf16x8 pf = *(const bf16x8*)&PpW[fr * PST + kk * 32 + fq * 8];
                    __builtin_amdgcn_s_setprio(1);
                    #pragma unroll
                    for (int mt = 0; mt < 4; ++mt)
                        ot[mt] = __builtin_amdgcn_mfma_f32_16x16x32_bf16(vf[mt], pf, ot[mt], 0, 0, 0);
                    __builtin_amdgcn_s_setprio(0);
                }
            } else {
                #pragma unroll
                for (int kk = 0; kk < 2; ++kk) {
                    bf16x8 kf[4];
                    #pragma unroll
                    for (int mt = 0; mt < 4; ++mt)
                        kf[mt] = *(const bf16x8*)((const char*)Kb + (mt * 16 + fr) * 128 + ((kk * 64 + fq * 16) ^ xrw));
                    #pragma unroll
                    for (int mt = 0; mt < 4; ++mt)
                        if (k0 + mt * 16 <= wq0 + 15)
                            st[mt] = __builtin_amdgcn_mfma_f32_16x16x32_bf16(kf[mt], qf[kk], st[mt], 0, 0, 0);
                }
                #pragma unroll
                for (int mt = 0; mt < 4; ++mt) {
                    const int kb0 = k0 + mt * 16 + fq * 4;
                    float pr[4];
                    #pragma unroll
                    for (int r = 0; r < 4; ++r) {
                        const float e = EXP2(st[mt][r]);
                        pr[r] = (kb0 + r > qrow) ? 0.f : e;
                    }
                    lp += (pr[0] + pr[1]) + (pr[2] + pr[3]);
                    uint2 w;
                    w.x = cvtpk2bf(pr[0], pr[1]);
                    w.y = cvtpk2bf(pr[2], pr[3]);
                    *(uint2*)&PpW[fr * PST + mt * 16 + fq * 4] = w;
                }
                #pragma unroll
                for (int kk = 0; kk < 2; ++kk) {
                    if (k0 + kk * 32 <= wq0 + 15) {
                        bf16x8 vf[4];
                        #pragma unroll
                        for (int mt = 0; mt < 4; ++mt)
                            vf[mt] = *(const bf16x8*)((const char*)Vb + (mt * 16 + fr) * 128 + ((kk * 64 + fq * 16) ^ xrw));
                        bf16x8 pf = *(const bf16x8*)&PpW[fr * PST + kk * 32 + fq * 8];
                        #pragma unroll
                        for (int mt = 0; mt < 4; ++mt)
                            ot[mt] = __builtin_amdgcn_mfma_f32_16x16x32_bf16(vf[mt], pf, ot[mt], 0, 0, 0);
                    }
                }
            }
            __syncthreads();   // drains stage loads + all waves done with cur
            cur ^= 1;
        }

        // epilogue: reduce l over fq lanes, normalize, store O^T -> ob [B,S,D]
        float l = lp;
        l += __shfl_xor(l, 16);
        l += __shfl_xor(l, 32);
        const float inv = 1.0f / l;
        #pragma unroll
        for (int mt = 0; mt < 4; ++mt) {
            uint2 w;
            w.x = cvtpk2bf(ot[mt][0] * inv, ot[mt][1] * inv);
            w.y = cvtpk2bf(ot[mt][2] * inv, ot[mt][3] * inv);
            *(uint2*)&ob[((size_t)b * S_ + qrow) * D_ + h * HD_ + mt * 16 + fq * 4] = w;
        }
    }
}

// ---------------- LayerNorm (residual already fused into gemm_p) -----------
__global__ __launch_bounds__(256) void resln(float* __restrict__ out,
                                             const float* __restrict__ g,
                                             const float* __restrict__ bb) {
    __shared__ float red[256];
    const int row = blockIdx.x, tid = threadIdx.x;
    const size_t off = (size_t)row * D_ + tid * 4;

    float4 y = *(const float4*)&out[off];

    float sum = y.x + y.y + y.z + y.w;
    red[tid] = sum;
    __syncthreads();
    #pragma unroll
    for (int st = 128; st > 0; st >>= 1) {
        if (tid < st) red[tid] += red[tid + st];
        __syncthreads();
    }
    const float mu = red[0] * (1.0f / D_);
    __syncthreads();

    float dx = y.x - mu, dy = y.y - mu, dz = y.z - mu, dw = y.w - mu;
    red[tid] = dx * dx + dy * dy + dz * dz + dw * dw;
    __syncthreads();
    #pragma unroll
    for (int st = 128; st > 0; st >>= 1) {
        if (tid < st) red[tid] += red[tid + st];
        __syncthreads();
    }
    const float var = red[0] * (1.0f / D_);
    const float inv = rsqrtf(var + 1e-5f);

    float4 gg = *(const float4*)&g[tid * 4];
    float4 bv = *(const float4*)&bb[tid * 4];
    float4 r;
    r.x = dx * inv * gg.x + bv.x;
    r.y = dy * inv * gg.y + bv.y;
    r.z = dz * inv * gg.z + bv.z;
    r.w = dw * inv * gg.w + bv.w;
    *(float4*)&out[off] = r;
}

extern "C" void kernel_launch(void* const* d_in, const int* in_sizes, int n_in,
                              void* d_out, int out_size, void* d_ws, size_t ws_size,
                              hipStream_t stream) {
    const float* x    = (const float*)d_in[0];
    const float* Wq   = (const float*)d_in[1];
    const float* bq   = (const float*)d_in[2];
    const float* Wk   = (const float*)d_in[3];
    const float* bk   = (const float*)d_in[4];
    const float* Wv   = (const float*)d_in[5];
    const float* bv   = (const float*)d_in[6];
    const float* Wp   = (const float*)d_in[7];
    const float* bp   = (const float*)d_in[8];
    const float* ln_g = (const float*)d_in[9];
    const float* ln_b = (const float*)d_in[10];

    float* out = (float*)d_out;

    char* ws = (char*)d_ws;
    ushort* qb  = (ushort*)ws;
    ushort* kb  = (ushort*)(ws + (size_t)16 * (1 << 20));
    ushort* vtb = (ushort*)(ws + (size_t)32 * (1 << 20));
    ushort* xb  = (ushort*)(ws + (size_t)48 * (1 << 20));
    ushort* ob  = (ushort*)(ws + (size_t)64 * (1 << 20));
    ushort* wtq = (ushort*)(ws + (size_t)80 * (1 << 20));
    ushort* wtk = (ushort*)(ws + (size_t)82 * (1 << 20));
    ushort* wtv = (ushort*)(ws + (size_t)84 * (1 << 20));
    ushort* wtp = (ushort*)(ws + (size_t)86 * (1 << 20));

    // convert x + transpose/convert all 4 weights in one launch
    prep<<<dim3(4096, 1, 2), 256, 0, stream>>>(x, xb, Wq, Wk, Wv, Wp, wtq, wtk, wtv, wtp);

    // Q,K -> [B,H,S,HD]; Vt -> [B,H,HD,S]  (one fused launch, 768 blocks)
    gemm_qkvt<<<dim3(M_ / 128, D_ / 256, 3), 512, 0, stream>>>(
        xb, wtq, wtk, wtv, bq, bk, bv, qb, kb, vtb);

    // block-cooperative LDS-staged flash attention -> ob bf16 [B,S,D]
    attn_mfma<<<dim3(64, 8), 512, 0, stream>>>(qb, kb, vtb, ob);

    // out-projection + bias + residual, then LN
    gemm_p<<<dim3(D_ / GN, M_ / GM), 256, 0, stream>>>(ob, wtp, bp, x, out);
    resln<<<M_, 256, 0, stream>>>(out, ln_g, ln_b);
}